// Round 7
// baseline (15589.229 us; speedup 1.0000x reference)
//
#include <hip/hip_runtime.h>

// ---------------------------------------------------------------------------
// LSTM network: x_proj GEMM -> persistent-kernel recurrence -> out GEMM -> LSM
// S=8192, I=H=O=1024.  bf16 MFMA compute, f32 state/output.
// R9: halve exchange participants: 32 WGs x 512 threads, 32 units/WG.
//   Theory: exchange floor is MALL hot-line queue depth (= #reader WGs per
//   line, invariant 64 across R2/R5-R8).  Halving WGs halves the queue.
//   - afr[2][16] (128 VGPR) weight residency; 32 MFMAs/wave as 8 chains of 4
//     reusing the same 16 LDS b-reads.
//   - epilogue wave 0: 2 units/lane (c0,c1), 16 tagged words/WG.
//   - poll (waves 1-4, dwordx4 sc0sc1 pair probes + agent fallback), xp
//     staging (wave 5, 128 f32), __syncthreads barriers: R7-proven structure.
// ---------------------------------------------------------------------------

using u16 = unsigned short;
using u32 = unsigned int;
using u64 = unsigned long long;

typedef short  short8  __attribute__((ext_vector_type(8)));   // 8 x bf16 frag
typedef float  floatx4 __attribute__((ext_vector_type(4)));
typedef u32    uintx4  __attribute__((ext_vector_type(4)));

#define S_LEN 8192
#define NPROD 32          // producer workgroups in recurrence (H/32)

__device__ __forceinline__ u16 f2bf(float f) {
    u32 u = __float_as_uint(f);
    u += 0x7FFFu + ((u >> 16) & 1u);     // round-to-nearest-even
    return (u16)(u >> 16);
}

__device__ __forceinline__ floatx4 mfma16(short8 a, short8 b, floatx4 c) {
    return __builtin_amdgcn_mfma_f32_16x16x32_bf16(a, b, c, 0, 0, 0);
}

// one device-coherent 16B probe of a word pair (single RTT, both tags)
#define PROBE(dst, srcp)                                               \
    asm volatile("global_load_dwordx4 %0, %1, off sc0 sc1"             \
                 : "=&v"(dst) : "v"(srcp) : "memory")

// ---------------- conversion / init kernels ----------------

__global__ void cvt_f32_bf16(const float* __restrict__ src, u16* __restrict__ dst, int n) {
    for (int i = blockIdx.x * blockDim.x + threadIdx.x; i < n; i += gridDim.x * blockDim.x)
        dst[i] = f2bf(src[i]);
}

__global__ void bias_comb_k(const float* __restrict__ a, const float* __restrict__ b,
                            float* __restrict__ o) {
    int i = blockIdx.x * blockDim.x + threadIdx.x;
    if (i < 4096) o[i] = a[i] + b[i];
}

__global__ void init_hbuf(u64* __restrict__ hbuf) {
    hbuf[blockIdx.x * 256 + threadIdx.x] = 0ull;   // grid 4 x 256 = 1024 words
}

// ---------------- GEMM: C[m,n] = sum_k A[m,k]*B[n,k] + bias[n] ----------------
// A: [M,K] bf16 row-major; B: [N,K] bf16 row-major; C: [M,N] f32.
// Block tile 128x64 (4 waves of 64x32), mfma 16x16x32 bf16, frags direct from global.

__global__ __launch_bounds__(256) void gemm_bt(const u16* __restrict__ A,
                                               const u16* __restrict__ B,
                                               const float* __restrict__ bias,
                                               float* __restrict__ C,
                                               int M, int N, int K) {
    const int tid = threadIdx.x;
    const int l = tid & 63, w = tid >> 6;
    const int m0 = blockIdx.x * 128 + (w >> 1) * 64;
    const int n0 = blockIdx.y * 64 + (w & 1) * 32;
    const int lr = l & 15, lk = (l >> 4) * 8;

    floatx4 acc[4][2];
#pragma unroll
    for (int i = 0; i < 4; i++)
#pragma unroll
        for (int j = 0; j < 2; j++) acc[i][j] = floatx4{0.f, 0.f, 0.f, 0.f};

    const u16* Ap = A + (size_t)(m0 + lr) * K + lk;
    const u16* Bp = B + (size_t)(n0 + lr) * K + lk;

    for (int k0 = 0; k0 < K; k0 += 32) {
        short8 a0 = *(const short8*)(Ap + k0);
        short8 a1 = *(const short8*)(Ap + (size_t)16 * K + k0);
        short8 a2 = *(const short8*)(Ap + (size_t)32 * K + k0);
        short8 a3 = *(const short8*)(Ap + (size_t)48 * K + k0);
        short8 b0 = *(const short8*)(Bp + k0);
        short8 b1 = *(const short8*)(Bp + (size_t)16 * K + k0);
        acc[0][0] = mfma16(a0, b0, acc[0][0]); acc[0][1] = mfma16(a0, b1, acc[0][1]);
        acc[1][0] = mfma16(a1, b0, acc[1][0]); acc[1][1] = mfma16(a1, b1, acc[1][1]);
        acc[2][0] = mfma16(a2, b0, acc[2][0]); acc[2][1] = mfma16(a2, b1, acc[2][1]);
        acc[3][0] = mfma16(a3, b0, acc[3][0]); acc[3][1] = mfma16(a3, b1, acc[3][1]);
    }

    const int rr = (l >> 4) * 4;
#pragma unroll
    for (int j = 0; j < 2; j++) {
        const int n = n0 + j * 16 + lr;
        const float bv = bias[n];
#pragma unroll
        for (int i = 0; i < 4; i++) {
            const int m = m0 + i * 16 + rr;
#pragma unroll
            for (int r = 0; r < 4; r++)
                C[(size_t)(m + r) * N + n] = acc[i][j][r] + bv;
        }
    }
}

// ---------------- persistent LSTM recurrence ----------------
// 32 WGs x 512 threads (8 waves). WG p owns hidden units [32p, 32p+32).
// Wave w: gate g = w&3, K-half kh = w>>2, BOTH 16-row tiles (units +0..16,
// +16..32): afr[2][16] in regs (128 VGPR), 32 MFMAs as 8 chains of 4 reusing
// 16 LDS b-reads.  h exchanged via tagged 64-bit words (hi32 = version,
// lo32 = 2xbf16), parity double-buffered.
// Roles: waves 1-4 poll (dwordx4 pair probes); wave 5 stages xp (128 f32);
// wave 0 epilogue (2 units/lane) + 16 tagged stores; waves 6,7 matvec only.

__device__ __forceinline__ float sig_f(float x) {
    return __builtin_amdgcn_rcpf(1.f + __expf(-x));
}
__device__ __forceinline__ float tanh_f(float x) {
    return 1.f - 2.f * __builtin_amdgcn_rcpf(1.f + __expf(2.f * x));
}

__global__ __launch_bounds__(512, 2) void lstm_rec(const u16* __restrict__ Whhb,
                                                   const float* __restrict__ xp,
                                                   u64* __restrict__ hbuf,
                                                   u32* __restrict__ hs) {
    const int p = blockIdx.x;
    const int tid = threadIdx.x;
    const int l = tid & 63, w = tid >> 6;
    const int g = w & 3;          // gate (i,f,g,o)
    const int kh = w >> 2;        // K half (0: k<512, 1: k>=512)

    __shared__ u32 h_lds[512];        // 1024 bf16 = current h (global layout)
    __shared__ float dots2[256];      // [tile][kh][g*16+jj]
    __shared__ float xp_lds[2][128];  // xp staged by wave 5, parity buffered

    // preload A-frags, both tiles:
    // tile j row: g*1024 + p*32 + j*16 + (l&15), k = kh*512 + kb*32 + (l>>4)*8
    short8 afr0[16], afr1[16];
    {
        const u16* wr0 = Whhb + (size_t)(g * 1024 + p * 32 + (l & 15)) * 1024
                        + kh * 512 + ((l >> 4) * 8);
        const u16* wr1 = wr0 + (size_t)16 * 1024;
#pragma unroll
        for (int kb = 0; kb < 16; ++kb) {
            afr0[kb] = *(const short8*)(wr0 + kb * 32);
            afr1[kb] = *(const short8*)(wr1 + kb * 32);
        }
    }
    h_lds[tid] = 0u;
    if (tid < 256) ((u32*)dots2)[tid] = 0u;

    float c0 = 0.f, c1 = 0.f;     // wave 0, lanes < 16: c for units l, l+16
    // wave-5 xp staging addresses: lane l covers gate (l>>4), units (l&15), +16
    const float* xprow = xp + (size_t)(l >> 4) * 1024 + p * 32 + (l & 15);
    if (w == 5) {                 // prefill xp(0)
        xp_lds[0][(l >> 4) * 32 + (l & 15)]      = xprow[0];
        xp_lds[0][(l >> 4) * 32 + (l & 15) + 16] = xprow[16];
    }
    __syncthreads();

    const u32* hb_base = &h_lds[kh * 256 + (l >> 4) * 4];
    const int pi = (w - 1) * 64 + l;         // pair index (valid for w=1..4)

    for (int t = 0; t < S_LEN; ++t) {
        if (w == 5) {
            // stage xp(t+1); load drains under the others' poll window
            int tn = (t + 1 < S_LEN) ? t + 1 : S_LEN - 1;
            const float* r = xprow + (size_t)tn * 4096;
            xp_lds[(t + 1) & 1][(l >> 4) * 32 + (l & 15)]      = r[0];
            xp_lds[(t + 1) & 1][(l >> 4) * 32 + (l & 15) + 16] = r[16];
        } else if (w >= 1 && w <= 4 && t > 0) {
            // poll word pair (2*pi, 2*pi+1) of h version t (parity t&1)
            u64* src0 = hbuf + (size_t)(t & 1) * 512 + 2 * pi;
            const u32 want = (u32)t;
            uintx4 q;
            bool got = false;
            for (int it = 0; it < 4096 && !got; ++it) {
                asm volatile("global_load_dwordx4 %0, %1, off sc0 sc1\n\t"
                             "s_waitcnt vmcnt(0)"
                             : "=&v"(q) : "v"(src0) : "memory");
                got = (q.y == want) && (q.w == want);
            }
            while (!got) {   // proven agent-scope fallback (hang-proof)
                u64 a = __hip_atomic_load(src0, __ATOMIC_RELAXED,
                                          __HIP_MEMORY_SCOPE_AGENT);
                u64 b = __hip_atomic_load(src0 + 1, __ATOMIC_RELAXED,
                                          __HIP_MEMORY_SCOPE_AGENT);
                if ((u32)(a >> 32) == want && (u32)(b >> 32) == want) {
                    q.x = (u32)a; q.z = (u32)b; got = true;
                }
            }
            h_lds[2 * pi]     = q.x;
            h_lds[2 * pi + 1] = q.z;
        }
        __syncthreads();   // sync1: h(t) complete in LDS

        // matvec: 2 tiles x 16 MFMAs = 8 interleaved chains of 4,
        // reusing the same 16 LDS b-reads across tiles
        floatx4 a00 = floatx4{0,0,0,0}, a01 = floatx4{0,0,0,0};
        floatx4 a02 = floatx4{0,0,0,0}, a03 = floatx4{0,0,0,0};
        floatx4 a10 = floatx4{0,0,0,0}, a11 = floatx4{0,0,0,0};
        floatx4 a12 = floatx4{0,0,0,0}, a13 = floatx4{0,0,0,0};
#pragma unroll
        for (int kb = 0; kb < 16; kb += 4) {
            uintx4 b0 = *(const uintx4*)(hb_base + (kb + 0) * 16);
            uintx4 b1 = *(const uintx4*)(hb_base + (kb + 1) * 16);
            uintx4 b2 = *(const uintx4*)(hb_base + (kb + 2) * 16);
            uintx4 b3 = *(const uintx4*)(hb_base + (kb + 3) * 16);
            a00 = mfma16(afr0[kb + 0], __builtin_bit_cast(short8, b0), a00);
            a10 = mfma16(afr1[kb + 0], __builtin_bit_cast(short8, b0), a10);
            a01 = mfma16(afr0[kb + 1], __builtin_bit_cast(short8, b1), a01);
            a11 = mfma16(afr1[kb + 1], __builtin_bit_cast(short8, b1), a11);
            a02 = mfma16(afr0[kb + 2], __builtin_bit_cast(short8, b2), a02);
            a12 = mfma16(afr1[kb + 2], __builtin_bit_cast(short8, b2), a12);
            a03 = mfma16(afr0[kb + 3], __builtin_bit_cast(short8, b3), a03);
            a13 = mfma16(afr1[kb + 3], __builtin_bit_cast(short8, b3), a13);
        }
        floatx4 s0 = (a00 + a01) + (a02 + a03);
        floatx4 s1 = (a10 + a11) + (a12 + a13);
        if ((l & 15) == 0) {        // column 0 of D holds the dot products
            const int q = l >> 4;
#pragma unroll
            for (int r = 0; r < 4; ++r) {
                dots2[kh * 64 + g * 16 + q * 4 + r]       = s0[r];
                dots2[128 + kh * 64 + g * 16 + q * 4 + r] = s1[r];
            }
        }
        __syncthreads();   // sync2: dots complete

        if (w == 0) {   // epilogue: lane l -> gate l>>4, units (l&15), (l&15)+16
            float xc0 = xp_lds[t & 1][(l >> 4) * 32 + (l & 15)];
            float xc1 = xp_lds[t & 1][(l >> 4) * 32 + (l & 15) + 16];
            float a0 = dots2[l] + dots2[64 + l] + xc0;
            float a1 = dots2[128 + l] + dots2[192 + l] + xc1;
            float act0 = ((l >> 4) == 2) ? tanh_f(a0) : sig_f(a0);
            float act1 = ((l >> 4) == 2) ? tanh_f(a1) : sig_f(a1);
            const int jj = l & 15;
            float fi0 = __shfl(act0, jj),      fi1 = __shfl(act1, jj);
            float ff0 = __shfl(act0, 16 + jj), ff1 = __shfl(act1, 16 + jj);
            float fg0 = __shfl(act0, 32 + jj), fg1 = __shfl(act1, 32 + jj);
            float fo0 = __shfl(act0, 48 + jj), fo1 = __shfl(act1, 48 + jj);
            if (l < 16) {
                c0 = ff0 * c0 + fi0 * fg0;
                c1 = ff1 * c1 + fi1 * fg1;
                float h0 = fo0 * tanh_f(c0);
                float h1 = fo1 * tanh_f(c1);
                u16 hb0 = f2bf(h0), hb1 = f2bf(h1);
                u32 o0 = (u32)__shfl_down((int)hb0, 1);
                u32 o1 = (u32)__shfl_down((int)hb1, 1);
                if ((l & 1) == 0) {
                    u32 pk0 = (u32)hb0 | (o0 << 16);     // units l, l+1
                    u32 pk1 = (u32)hb1 | (o1 << 16);     // units 16+l, 16+l+1
                    int i0 = p * 16 + (l >> 1);
                    int i1 = p * 16 + 8 + (l >> 1);
                    u64 tv0 = ((u64)(u32)(t + 1) << 32) | (u64)pk0;
                    u64 tv1 = ((u64)(u32)(t + 1) << 32) | (u64)pk1;
                    const size_t par = (size_t)((t + 1) & 1) * 512;
                    // same-parity stores of 2 steps ago drained at the
                    // __syncthreads (per-wave vmcnt(0)) barriers in between.
                    __hip_atomic_store(&hbuf[par + i0], tv0,
                                       __ATOMIC_RELAXED, __HIP_MEMORY_SCOPE_AGENT);
                    __hip_atomic_store(&hbuf[par + i1], tv1,
                                       __ATOMIC_RELAXED, __HIP_MEMORY_SCOPE_AGENT);
                    hs[(size_t)t * 512 + i0] = pk0;      // hs[t] bf16 row
                    hs[(size_t)t * 512 + i1] = pk1;
                }
            }
        }
    }
}

// ---------------- row log_softmax, in place, 1024 cols ----------------

__global__ __launch_bounds__(256) void lsm_k(float* __restrict__ C) {
    const int tid = threadIdx.x;
    float* p = C + (size_t)blockIdx.x * 1024;
    float v0 = p[tid], v1 = p[tid + 256], v2 = p[tid + 512], v3 = p[tid + 768];
    float mx = fmaxf(fmaxf(v0, v1), fmaxf(v2, v3));
#pragma unroll
    for (int o = 1; o < 64; o <<= 1) mx = fmaxf(mx, __shfl_xor(mx, o));
    __shared__ float red[4];
    const int w = tid >> 6, l = tid & 63;
    if (l == 0) red[w] = mx;
    __syncthreads();
    mx = fmaxf(fmaxf(red[0], red[1]), fmaxf(red[2], red[3]));
    float s = __expf(v0 - mx) + __expf(v1 - mx) + __expf(v2 - mx) + __expf(v3 - mx);
#pragma unroll
    for (int o = 1; o < 64; o <<= 1) s += __shfl_xor(s, o);
    __syncthreads();
    if (l == 0) red[w] = s;
    __syncthreads();
    s = red[0] + red[1] + red[2] + red[3];
    float ls = __logf(s) + mx;
    p[tid] = v0 - ls; p[tid + 256] = v1 - ls; p[tid + 512] = v2 - ls; p[tid + 768] = v3 - ls;
}

// ---------------- launch ----------------

extern "C" void kernel_launch(void* const* d_in, const int* in_sizes, int n_in,
                              void* d_out, int out_size, void* d_ws, size_t ws_size,
                              hipStream_t stream) {
    const float* x     = (const float*)d_in[0];
    const float* W_ih  = (const float*)d_in[1];
    const float* W_hh  = (const float*)d_in[2];
    const float* b_ih  = (const float*)d_in[3];
    const float* b_hh  = (const float*)d_in[4];
    const float* W_out = (const float*)d_in[5];
    const float* b_out = (const float*)d_in[6];

    char* ws = (char*)d_ws;
    // workspace layout (bytes)
    u16*   xb    = (u16*)(ws + 0);                     // 8192x1024 bf16   16 MB
    u16*   Wihb  = (u16*)(ws + 16777216);              // 4096x1024 bf16    8 MB
    u16*   Whhb  = (u16*)(ws + 25165824);              // 4096x1024 bf16    8 MB
    u16*   Woutb = (u16*)(ws + 33554432);              // 1024x1024 bf16    2 MB
    float* biasc = (float*)(ws + 35651584);            // 4096 f32         16 KB
    u64*   hbuf  = (u64*)(ws + 35667968);              // 2x512 u64         8 KB
    u32*   hs    = (u32*)(ws + 35676160);              // 8192x512 u32     16 MB
    float* xp    = (float*)(ws + 52453376);            // 8192x4096 f32   128 MB

    init_hbuf<<<4, 256, 0, stream>>>(hbuf);
    cvt_f32_bf16<<<2048, 256, 0, stream>>>(x, xb, 8192 * 1024);
    cvt_f32_bf16<<<1024, 256, 0, stream>>>(W_ih, Wihb, 4096 * 1024);
    cvt_f32_bf16<<<1024, 256, 0, stream>>>(W_hh, Whhb, 4096 * 1024);
    cvt_f32_bf16<<<256, 256, 0, stream>>>(W_out, Woutb, 1024 * 1024);
    bias_comb_k<<<16, 256, 0, stream>>>(b_ih, b_hh, biasc);

    // x_proj = x @ W_ih^T + (b_ih+b_hh)
    gemm_bt<<<dim3(64, 64), 256, 0, stream>>>(xb, Wihb, biasc, xp, 8192, 4096, 1024);

    // recurrence (persistent, 32 WGs, all co-resident)
    lstm_rec<<<NPROD, 512, 0, stream>>>(Whhb, xp, hbuf, hs);

    // logits = hs @ W_out^T + b_out
    gemm_bt<<<dim3(64, 16), 256, 0, stream>>>((const u16*)hs, Woutb, b_out, (float*)d_out,
                                              8192, 1024, 1024);

    // log_softmax rows, in place
    lsm_k<<<8192, 256, 0, stream>>>((float*)d_out);
}

// Round 8
// 13811.746 us; speedup vs baseline: 1.1287x; 1.1287x over previous
//
#include <hip/hip_runtime.h>

// ---------------------------------------------------------------------------
// LSTM network: x_proj GEMM -> persistent-kernel recurrence -> out GEMM -> LSM
// S=8192, I=H=O=1024.  bf16 MFMA compute, f32 state/output.
// R10: multicast-replica exchange — clean isolation of MALL reader-queue depth.
//   Producers store each tagged word to 8 replica regions (8 pipelined
//   agent-scope stores); consumer WG p polls ONLY region p&7, so each MALL
//   line serves 8 reader WGs instead of 64.  Everything else is byte-identical
//   to R7 (= R2 performance): 64 WGs, 16 units/WG, waves 1-4 poll pairs via
//   dwordx4 sc0sc1 + agent fallback, wave 5 stages xp, wave 0 epilogue,
//   __syncthreads barriers.  hbuf: 8 regions x 2 parities x 512 u64 = 64 KB.
// ---------------------------------------------------------------------------

using u16 = unsigned short;
using u32 = unsigned int;
using u64 = unsigned long long;

typedef short  short8  __attribute__((ext_vector_type(8)));   // 8 x bf16 frag
typedef float  floatx4 __attribute__((ext_vector_type(4)));
typedef u32    uintx4  __attribute__((ext_vector_type(4)));

#define S_LEN 8192
#define NPROD 64          // producer workgroups in recurrence (H/16)
#define NREP  8           // multicast replica regions

__device__ __forceinline__ u16 f2bf(float f) {
    u32 u = __float_as_uint(f);
    u += 0x7FFFu + ((u >> 16) & 1u);     // round-to-nearest-even
    return (u16)(u >> 16);
}

__device__ __forceinline__ floatx4 mfma16(short8 a, short8 b, floatx4 c) {
    return __builtin_amdgcn_mfma_f32_16x16x32_bf16(a, b, c, 0, 0, 0);
}

// ---------------- conversion / init kernels ----------------

__global__ void cvt_f32_bf16(const float* __restrict__ src, u16* __restrict__ dst, int n) {
    for (int i = blockIdx.x * blockDim.x + threadIdx.x; i < n; i += gridDim.x * blockDim.x)
        dst[i] = f2bf(src[i]);
}

__global__ void bias_comb_k(const float* __restrict__ a, const float* __restrict__ b,
                            float* __restrict__ o) {
    int i = blockIdx.x * blockDim.x + threadIdx.x;
    if (i < 4096) o[i] = a[i] + b[i];
}

__global__ void init_hbuf(u64* __restrict__ hbuf) {
    hbuf[blockIdx.x * 256 + threadIdx.x] = 0ull;   // grid 32 x 256 = 8192 words
}

// ---------------- GEMM: C[m,n] = sum_k A[m,k]*B[n,k] + bias[n] ----------------
// A: [M,K] bf16 row-major; B: [N,K] bf16 row-major; C: [M,N] f32.
// Block tile 128x64 (4 waves of 64x32), mfma 16x16x32 bf16, frags direct from global.

__global__ __launch_bounds__(256) void gemm_bt(const u16* __restrict__ A,
                                               const u16* __restrict__ B,
                                               const float* __restrict__ bias,
                                               float* __restrict__ C,
                                               int M, int N, int K) {
    const int tid = threadIdx.x;
    const int l = tid & 63, w = tid >> 6;
    const int m0 = blockIdx.x * 128 + (w >> 1) * 64;
    const int n0 = blockIdx.y * 64 + (w & 1) * 32;
    const int lr = l & 15, lk = (l >> 4) * 8;

    floatx4 acc[4][2];
#pragma unroll
    for (int i = 0; i < 4; i++)
#pragma unroll
        for (int j = 0; j < 2; j++) acc[i][j] = floatx4{0.f, 0.f, 0.f, 0.f};

    const u16* Ap = A + (size_t)(m0 + lr) * K + lk;
    const u16* Bp = B + (size_t)(n0 + lr) * K + lk;

    for (int k0 = 0; k0 < K; k0 += 32) {
        short8 a0 = *(const short8*)(Ap + k0);
        short8 a1 = *(const short8*)(Ap + (size_t)16 * K + k0);
        short8 a2 = *(const short8*)(Ap + (size_t)32 * K + k0);
        short8 a3 = *(const short8*)(Ap + (size_t)48 * K + k0);
        short8 b0 = *(const short8*)(Bp + k0);
        short8 b1 = *(const short8*)(Bp + (size_t)16 * K + k0);
        acc[0][0] = mfma16(a0, b0, acc[0][0]); acc[0][1] = mfma16(a0, b1, acc[0][1]);
        acc[1][0] = mfma16(a1, b0, acc[1][0]); acc[1][1] = mfma16(a1, b1, acc[1][1]);
        acc[2][0] = mfma16(a2, b0, acc[2][0]); acc[2][1] = mfma16(a2, b1, acc[2][1]);
        acc[3][0] = mfma16(a3, b0, acc[3][0]); acc[3][1] = mfma16(a3, b1, acc[3][1]);
    }

    const int rr = (l >> 4) * 4;
#pragma unroll
    for (int j = 0; j < 2; j++) {
        const int n = n0 + j * 16 + lr;
        const float bv = bias[n];
#pragma unroll
        for (int i = 0; i < 4; i++) {
            const int m = m0 + i * 16 + rr;
#pragma unroll
            for (int r = 0; r < 4; r++)
                C[(size_t)(m + r) * N + n] = acc[i][j][r] + bv;
        }
    }
}

// ---------------- persistent LSTM recurrence ----------------
// 64 WGs x 512 threads (8 waves). WG p owns hidden units [16p, 16p+16).
// Wave w: gate g = w&3, K-half kh = w>>2. A-frags (16 per thread) in regs.
// h exchanged via tagged 64-bit words (hi32 = version, lo32 = 2xbf16),
// parity double-buffered, MULTICAST to 8 replica regions; consumer WG p
// polls region p&7 only (8 reader WGs per MALL line instead of 64).
// Roles: waves 1-4 poll (one dwordx4 = word pair each); wave 5 stages xp;
// wave 0 computes epilogue + 8 replica stores; waves 6,7 only matvec.

__device__ __forceinline__ float sig_f(float x) {
    return __builtin_amdgcn_rcpf(1.f + __expf(-x));
}
__device__ __forceinline__ float tanh_f(float x) {
    return 1.f - 2.f * __builtin_amdgcn_rcpf(1.f + __expf(2.f * x));
}

__global__ __launch_bounds__(512, 2) void lstm_rec(const u16* __restrict__ Whhb,
                                                   const float* __restrict__ xp,
                                                   u64* __restrict__ hbuf,
                                                   u32* __restrict__ hs) {
    const int p = blockIdx.x;
    const int tid = threadIdx.x;
    const int l = tid & 63, w = tid >> 6;
    const int g = w & 3;          // gate (i,f,g,o)
    const int kh = w >> 2;        // K half (0: k<512, 1: k>=512)

    __shared__ u32 h_lds[512];       // 1024 bf16 = current h
    __shared__ float dots[128];      // [kh][g*16+jj]
    __shared__ float xp_lds[2][64];  // xp staged by wave 5, parity buffered

    // preload A-frags: row g*1024 + 16p + (l&15), k = kh*512 + kb*32 + (l>>4)*8
    short8 afr[16];
    {
        const u16* wr = Whhb + (size_t)(g * 1024 + p * 16 + (l & 15)) * 1024
                       + kh * 512 + ((l >> 4) * 8);
#pragma unroll
        for (int kb = 0; kb < 16; ++kb) afr[kb] = *(const short8*)(wr + kb * 32);
    }
    h_lds[tid] = 0u;

    float c_state = 0.f;          // wave 0, lanes < 16
    const float* xprow = xp + (size_t)(l >> 4) * 1024 + p * 16 + (l & 15);
    if (w == 5) xp_lds[0][l] = xprow[0];    // prefill xp(0)
    __syncthreads();

    const int bofs = (l >> 4) * 4;
    const u32* hb_base = &h_lds[kh * 256 + bofs];
    const int pi = (w - 1) * 64 + l;         // pair index (valid for w=1..4)
    // this WG's replica region base (u64 index)
    u64* const myreg = hbuf + (size_t)(p & (NREP - 1)) * 1024;

    for (int t = 0; t < S_LEN; ++t) {
        float xc = 0.f;

        if (w == 0) {
            xc = xp_lds[t & 1][l];           // staged xp(t); no vmem issued
        } else if (w == 5) {
            // stage xp(t+1); load drains under the others' poll window
            int tn = (t + 1 < S_LEN) ? t + 1 : S_LEN - 1;
            xp_lds[(t + 1) & 1][l] = xprow[(size_t)tn * 4096];
        } else if (w <= 4 && t > 0) {
            // poll word pair (2*pi, 2*pi+1) of h version t (parity t&1)
            // in THIS WG's replica region only
            u64* src0 = myreg + (size_t)(t & 1) * 512 + 2 * pi;
            const u32 want = (u32)t;
            uintx4 q;
            bool got = false;
            for (int it = 0; it < 4096 && !got; ++it) {
                // one device-coherent 16B sample = both words, single RTT
                asm volatile("global_load_dwordx4 %0, %1, off sc0 sc1\n\t"
                             "s_waitcnt vmcnt(0)"
                             : "=&v"(q) : "v"(src0) : "memory");
                got = (q.y == want) && (q.w == want);
            }
            while (!got) {   // proven agent-scope fallback (hang-proof)
                u64 a = __hip_atomic_load(src0, __ATOMIC_RELAXED,
                                          __HIP_MEMORY_SCOPE_AGENT);
                u64 b = __hip_atomic_load(src0 + 1, __ATOMIC_RELAXED,
                                          __HIP_MEMORY_SCOPE_AGENT);
                if ((u32)(a >> 32) == want && (u32)(b >> 32) == want) {
                    q.x = (u32)a; q.z = (u32)b; got = true;
                }
            }
            h_lds[2 * pi]     = q.x;
            h_lds[2 * pi + 1] = q.z;
        }
        __syncthreads();   // sync1: h(t) complete in LDS

        // matvec over this wave's K-half: 16 MFMAs, 4 chains of 4
        floatx4 ac0 = floatx4{0,0,0,0}, ac1 = floatx4{0,0,0,0};
        floatx4 ac2 = floatx4{0,0,0,0}, ac3 = floatx4{0,0,0,0};
#pragma unroll
        for (int kb = 0; kb < 16; kb += 4) {
            uintx4 b0 = *(const uintx4*)(hb_base + (kb + 0) * 16);
            uintx4 b1 = *(const uintx4*)(hb_base + (kb + 1) * 16);
            uintx4 b2 = *(const uintx4*)(hb_base + (kb + 2) * 16);
            uintx4 b3 = *(const uintx4*)(hb_base + (kb + 3) * 16);
            ac0 = mfma16(afr[kb + 0], __builtin_bit_cast(short8, b0), ac0);
            ac1 = mfma16(afr[kb + 1], __builtin_bit_cast(short8, b1), ac1);
            ac2 = mfma16(afr[kb + 2], __builtin_bit_cast(short8, b2), ac2);
            ac3 = mfma16(afr[kb + 3], __builtin_bit_cast(short8, b3), ac3);
        }
        floatx4 acs = (ac0 + ac1) + (ac2 + ac3);
        if ((l & 15) == 0) {        // column 0 of D holds the dot products
            const int q = l >> 4;
#pragma unroll
            for (int r = 0; r < 4; ++r) dots[kh * 64 + g * 16 + q * 4 + r] = acs[r];
        }
        __syncthreads();   // sync2: dots complete

        if (w == 0) {   // wave-parallel epilogue (lane l: gate l>>4, unit l&15)
            float a = dots[l] + dots[64 + l] + xc;
            float act = ((l >> 4) == 2) ? tanh_f(a) : sig_f(a);
            const int jj = l & 15;
            float fi = __shfl(act, jj);
            float ff = __shfl(act, 16 + jj);
            float fg = __shfl(act, 32 + jj);
            float fo = __shfl(act, 48 + jj);
            if (l < 16) {
                c_state = ff * c_state + fi * fg;
                float h = fo * tanh_f(c_state);
                u16 hb16 = f2bf(h);
                u32 other = (u32)__shfl_down((int)hb16, 1);
                if ((l & 1) == 0) {
                    u32 pk = (u32)hb16 | (other << 16);
                    int pidx = p * 8 + (l >> 1);
                    u64 tv = ((u64)(u32)(t + 1) << 32) | (u64)pk;    // tagged word
                    const size_t off = (size_t)((t + 1) & 1) * 512 + pidx;
                    // multicast: one tagged store per replica region.
                    // same-parity stores of 2 steps ago drained at the
                    // __syncthreads (per-wave vmcnt(0)) barriers in between.
#pragma unroll
                    for (int r = 0; r < NREP; ++r)
                        __hip_atomic_store(&hbuf[(size_t)r * 1024 + off], tv,
                                           __ATOMIC_RELAXED, __HIP_MEMORY_SCOPE_AGENT);
                    hs[(size_t)t * 512 + pidx] = pk;                 // hs[t] bf16
                }
            }
        }
    }
}

// ---------------- row log_softmax, in place, 1024 cols ----------------

__global__ __launch_bounds__(256) void lsm_k(float* __restrict__ C) {
    const int tid = threadIdx.x;
    float* p = C + (size_t)blockIdx.x * 1024;
    float v0 = p[tid], v1 = p[tid + 256], v2 = p[tid + 512], v3 = p[tid + 768];
    float mx = fmaxf(fmaxf(v0, v1), fmaxf(v2, v3));
#pragma unroll
    for (int o = 1; o < 64; o <<= 1) mx = fmaxf(mx, __shfl_xor(mx, o));
    __shared__ float red[4];
    const int w = tid >> 6, l = tid & 63;
    if (l == 0) red[w] = mx;
    __syncthreads();
    mx = fmaxf(fmaxf(red[0], red[1]), fmaxf(red[2], red[3]));
    float s = __expf(v0 - mx) + __expf(v1 - mx) + __expf(v2 - mx) + __expf(v3 - mx);
#pragma unroll
    for (int o = 1; o < 64; o <<= 1) s += __shfl_xor(s, o);
    __syncthreads();
    if (l == 0) red[w] = s;
    __syncthreads();
    s = red[0] + red[1] + red[2] + red[3];
    float ls = __logf(s) + mx;
    p[tid] = v0 - ls; p[tid + 256] = v1 - ls; p[tid + 512] = v2 - ls; p[tid + 768] = v3 - ls;
}

// ---------------- launch ----------------

extern "C" void kernel_launch(void* const* d_in, const int* in_sizes, int n_in,
                              void* d_out, int out_size, void* d_ws, size_t ws_size,
                              hipStream_t stream) {
    const float* x     = (const float*)d_in[0];
    const float* W_ih  = (const float*)d_in[1];
    const float* W_hh  = (const float*)d_in[2];
    const float* b_ih  = (const float*)d_in[3];
    const float* b_hh  = (const float*)d_in[4];
    const float* W_out = (const float*)d_in[5];
    const float* b_out = (const float*)d_in[6];

    char* ws = (char*)d_ws;
    // workspace layout (bytes)
    u16*   xb    = (u16*)(ws + 0);                     // 8192x1024 bf16   16 MB
    u16*   Wihb  = (u16*)(ws + 16777216);              // 4096x1024 bf16    8 MB
    u16*   Whhb  = (u16*)(ws + 25165824);              // 4096x1024 bf16    8 MB
    u16*   Woutb = (u16*)(ws + 33554432);              // 1024x1024 bf16    2 MB
    float* biasc = (float*)(ws + 35651584);            // 4096 f32         16 KB
    u64*   hbuf  = (u64*)(ws + 35667968);              // 8x2x512 u64      64 KB
    u32*   hs    = (u32*)(ws + 35733504);              // 8192x512 u32     16 MB
    float* xp    = (float*)(ws + 52510720);            // 8192x4096 f32   128 MB

    init_hbuf<<<32, 256, 0, stream>>>(hbuf);
    cvt_f32_bf16<<<2048, 256, 0, stream>>>(x, xb, 8192 * 1024);
    cvt_f32_bf16<<<1024, 256, 0, stream>>>(W_ih, Wihb, 4096 * 1024);
    cvt_f32_bf16<<<1024, 256, 0, stream>>>(W_hh, Whhb, 4096 * 1024);
    cvt_f32_bf16<<<256, 256, 0, stream>>>(W_out, Woutb, 1024 * 1024);
    bias_comb_k<<<16, 256, 0, stream>>>(b_ih, b_hh, biasc);

    // x_proj = x @ W_ih^T + (b_ih+b_hh)
    gemm_bt<<<dim3(64, 64), 256, 0, stream>>>(xb, Wihb, biasc, xp, 8192, 4096, 1024);

    // recurrence (persistent, 64 WGs, all co-resident)
    lstm_rec<<<NPROD, 512, 0, stream>>>(Whhb, xp, hbuf, hs);

    // logits = hs @ W_out^T + b_out
    gemm_bt<<<dim3(64, 16), 256, 0, stream>>>((const u16*)hs, Woutb, b_out, (float*)d_out,
                                              8192, 1024, 1024);

    // log_softmax rows, in place
    lsm_k<<<8192, 256, 0, stream>>>((float*)d_out);
}